// Round 2
// baseline (28.285 us; speedup 1.0000x reference)
//
#include <hip/hip_runtime.h>

#define NPAIR (512 * 512)
#define NL 5
#define NH 8
#define ND 16
#define NE 10000
#define TPB 256
#define PPB 64   // pairs per block (4 lanes cooperate per pair)

// Single fused kernel, quad-cooperative gather:
// lane = (q, qd); the 4 lanes of quad q each load one float4 quarter of each
// 64B F-row, so one load instruction = one cache-line request per (pair,l):
// 5 line-lookups per pair (the floor) vs 20 in the 1-lane-per-pair version.
__global__ __launch_bounds__(256) void edge_fused_quad(
    const float* __restrict__ F,    // [E, D]
    const float* __restrict__ Wg,   // [L+1, H*D]
    const int* __restrict__ sp,     // [NPAIR, L] int32
    float* __restrict__ out)        // [H, NPAIR]
{
    __shared__ int spL[PPB * NL];   // 320 ints
    const int tid = threadIdx.x;
    const int base = blockIdx.x * PPB;

    // stage 64 pairs * 5 ints = 80 int4, coalesced
    if (tid < (PPB * NL) / 4)
        ((int4*)spL)[tid] = ((const int4*)(sp + (size_t)base * NL))[tid];
    __syncthreads();

    const int q  = tid >> 2;        // pair within block
    const int qd = tid & 3;         // quarter of the D dimension

    // 16 distinct addresses/wave, stride 5 (coprime 32): conflict-free,
    // 4 lanes per address broadcast.
    int e[NL];
#pragma unroll
    for (int l = 0; l < NL; ++l) e[l] = spL[q * NL + l];

    // gather: one float4 per row-quarter; quad covers the row in one line req
    float4 f[NL];
#pragma unroll
    for (int l = 0; l < NL; ++l) {
        const int idx = (e[l] >= 0) ? e[l] : 0;
        f[l] = *(const float4*)(F + (size_t)idx * ND + qd * 4);
    }

    float cnt = 0.f;
#pragma unroll
    for (int l = 0; l < NL; ++l) {
        if (e[l] < 0) f[l] = make_float4(0.f, 0.f, 0.f, 0.f);  // mask via zeroing
        else cnt += 1.f;
    }

    float acc[NH];
#pragma unroll
    for (int h = 0; h < NH; ++h) acc[h] = 0.f;

    // W quarter slab: 2.5 KB total, L1-resident; 4 distinct 16B addrs per
    // instruction -> 1 line lookup each.
    const float* __restrict__ Wq = Wg + NH * ND + qd * 4;   // row 1, this quarter
#pragma unroll
    for (int l = 0; l < NL; ++l) {
        const float4 fl = f[l];
#pragma unroll
        for (int h = 0; h < NH; ++h) {
            const float4 w = *(const float4*)(Wq + (l * NH + h) * ND);
            acc[h] += fl.x * w.x + fl.y * w.y + fl.z * w.z + fl.w * w.w;
        }
    }

    // intra-quad butterfly: sum the 4 quarter-dots (stays within the quad)
#pragma unroll
    for (int h = 0; h < NH; ++h) {
        acc[h] += __shfl_xor(acc[h], 1, 64);
        acc[h] += __shfl_xor(acc[h], 2, 64);
    }

    const float r = 1.0f / fmaxf(cnt, 1.f);
    const size_t p = (size_t)base + q;
    // lane qd stores planes qd*2+j: per instruction, 4 qd-groups x 16
    // consecutive floats = 8 aligned 64B segments over the 2 instructions.
#pragma unroll
    for (int j = 0; j < 2; ++j)
        __builtin_nontemporal_store(acc[qd * 2 + j] * r,
                                    out + (size_t)(qd * 2 + j) * NPAIR + p);
}

extern "C" void kernel_launch(void* const* d_in, const int* in_sizes, int n_in,
                              void* d_out, int out_size, void* d_ws, size_t ws_size,
                              hipStream_t stream) {
    (void)in_sizes; (void)n_in; (void)out_size; (void)d_ws; (void)ws_size;
    const float* F  = (const float*)d_in[0];   // edge_features_s [E, D]
    const float* Wg = (const float*)d_in[1];   // edge_weights [L+1, H*D]
    const int*   sp = (const int*)d_in[2];     // shortest_path_edges [N, N, L] int32
    float* out = (float*)d_out;                // [H, N, N]

    const int grid = NPAIR / PPB;              // 4096 blocks
    edge_fused_quad<<<grid, TPB, 0, stream>>>(F, Wg, sp, out);
}

// Round 4
// 23.550 us; speedup vs baseline: 1.2011x; 1.2011x over previous
//
#include <hip/hip_runtime.h>
#include <hip/hip_fp16.h>

#define NPAIR (512 * 512)
#define NL 5
#define NH 8
#define ND 16
#define NE 10000
#define TPB 256
#define GRID (NPAIR / TPB)               // 1024 blocks = 4/CU * 256 CU, co-resident
#define NROWS (NE * NL)                  // 50000 table rows (e,l)
#define NWBLK ((NROWS + TPB - 1) / TPB)  // 196 writer blocks
#define FLAGS_OFF (1u << 20)             // flags live at d_ws + 1MB (T uses 800KB)

// per-flag magic: poison-collision-proof barrier token (unknown poison value
// would have to equal one of these exactly; ~2^-32 per flag)
__device__ __forceinline__ unsigned magic_of(int i) {
    return 0xA5C37E19u ^ ((unsigned)i * 0x9E3779B1u);
}

// Single plain dispatch:
//  Phase A: threads g<50000 build T[e][l][h] = dot(F[e], W[1+l][h]) as fp16;
//           one row = 8 halfs = ONE 16B granule.
//  Software barrier: writer blocks release-store magic flags (AGENT scope ->
//           L2 writeback, T lands in L3); all blocks spin on the 196 flags.
//  Phase B: per pair, 5 gathers of 16B (vs 20 in baseline) -> 4x cut in the
//           measured ~2cyc/CU-per-granule VMEM term.
__global__ __launch_bounds__(256, 4) void edge_onepass(
    const float* __restrict__ F,    // [E, D]
    const float* __restrict__ Wg,   // [L+1, H*D]
    const int* __restrict__ sp,     // [NPAIR, L] int32
    float* __restrict__ out,        // [H, NPAIR]
    __half* __restrict__ T,         // [NROWS, NH] fp16 workspace
    unsigned* __restrict__ flags)   // [NWBLK] workspace
{
    __shared__ int spL[TPB * NL];   // 1280 ints
    const int tid = threadIdx.x;
    const int bid = blockIdx.x;
    const int g = bid * TPB + tid;

    // ---- issue sp staging first: latency hides under phase A + barrier ----
    const int4* __restrict__ spv = (const int4*)(sp + (size_t)bid * (TPB * NL));
    int4* spd = (int4*)spL;
#pragma unroll
    for (int i = 0; i < 2; ++i) {
        const int k = tid + i * TPB;
        if (k < (TPB * NL) / 4) spd[k] = spv[k];
    }

    // ---- Phase A: build fp16 table (blocks 0..195) ----
    if (g < NROWS) {
        const int e = g / NL;           // magic-mul div
        const int l = g - e * NL;
        const float4* __restrict__ fp = (const float4*)(F + (size_t)e * ND);
        const float4 f0 = fp[0], f1 = fp[1], f2 = fp[2], f3 = fp[3];
        const float* __restrict__ w0 = Wg + NH * ND + l * NH * ND;  // W row 1+l

        union { uint4 u; __half2 h[4]; } s;
#pragma unroll
        for (int hh = 0; hh < 4; ++hh) {
            float r2[2];
#pragma unroll
            for (int k = 0; k < 2; ++k) {
                const int h = hh * 2 + k;
                const float4* __restrict__ wp = (const float4*)(w0 + h * ND);
                const float4 wa = wp[0], wb = wp[1], wc = wp[2], wd = wp[3];
                float a;
                a  = f0.x * wa.x + f0.y * wa.y + f0.z * wa.z + f0.w * wa.w;
                a += f1.x * wb.x + f1.y * wb.y + f1.z * wb.z + f1.w * wb.w;
                a += f2.x * wc.x + f2.y * wc.y + f2.z * wc.z + f2.w * wc.w;
                a += f3.x * wd.x + f3.y * wd.y + f3.z * wd.z + f3.w * wd.w;
                r2[k] = a;
            }
            s.h[hh] = __floats2half2_rn(r2[0], r2[1]);
        }
        *(uint4*)(T + (size_t)g * NH) = s.u;   // one 16B store per row
    }

    // ---- writer signal: syncthreads drains vmem (all T stores done), then
    //      one release-store at AGENT scope (emits L2 writeback -> T in L3) ----
    if (bid < NWBLK) {
        __syncthreads();
        if (tid == 0)
            __hip_atomic_store(&flags[bid], magic_of(bid),
                               __ATOMIC_RELEASE, __HIP_MEMORY_SCOPE_AGENT);
    }

    // ---- spin barrier: thread t watches flag t (196 of 256 threads) ----
    if (tid < NWBLK) {
        const unsigned want = magic_of(tid);
        while (__hip_atomic_load(&flags[tid], __ATOMIC_RELAXED,
                                 __HIP_MEMORY_SCOPE_AGENT) != want)
            __builtin_amdgcn_s_sleep(2);
    }
    __syncthreads();   // also orders spL staging before phase B reads

    // ---- Phase B: gather + masked mean ----
    int e[NL];
#pragma unroll
    for (int l = 0; l < NL; ++l) e[l] = spL[tid * NL + l];  // stride-5, conflict-free

    float acc[NH];
#pragma unroll
    for (int h = 0; h < NH; ++h) acc[h] = 0.f;
    float cnt = 0.f;

#pragma unroll
    for (int l = 0; l < NL; ++l) {
        const int row = ((e[l] >= 0) ? e[l] : 0) * NL + l;
        const float m = (e[l] >= 0) ? 1.f : 0.f;
        cnt += m;
        union { uint4 u; __half2 h[4]; } t;
        t.u = *(const uint4*)(T + (size_t)row * NH);   // ONE 16B granule per (p,l)
#pragma unroll
        for (int hh = 0; hh < 4; ++hh) {
            const float2 v = __half22float2(t.h[hh]);
            acc[hh * 2 + 0] += m * v.x;
            acc[hh * 2 + 1] += m * v.y;
        }
    }

    const float r = 1.0f / fmaxf(cnt, 1.f);
    const size_t p = (size_t)g;
#pragma unroll
    for (int h = 0; h < NH; ++h)
        __builtin_nontemporal_store(acc[h] * r, out + (size_t)h * NPAIR + p);
}

extern "C" void kernel_launch(void* const* d_in, const int* in_sizes, int n_in,
                              void* d_out, int out_size, void* d_ws, size_t ws_size,
                              hipStream_t stream) {
    (void)in_sizes; (void)n_in; (void)out_size; (void)ws_size;
    const float* F  = (const float*)d_in[0];   // edge_features_s [E, D]
    const float* Wg = (const float*)d_in[1];   // edge_weights [L+1, H*D]
    const int*   sp = (const int*)d_in[2];     // shortest_path_edges [N,N,L] int32
    float* out = (float*)d_out;                // [H, N, N]
    __half* T = (__half*)d_ws;                 // 800 KB table
    unsigned* flags = (unsigned*)((char*)d_ws + FLAGS_OFF);

    edge_onepass<<<GRID, TPB, 0, stream>>>(F, Wg, sp, out, T, flags);
}

// Round 5
// 16.804 us; speedup vs baseline: 1.6832x; 1.4015x over previous
//
#include <hip/hip_runtime.h>
#include <hip/hip_fp16.h>

#define NPAIR (512 * 512)
#define NL 5
#define NH 8
#define ND 16
#define NE 10000
#define TPB 256
#define GRID (NPAIR / TPB)               // 1024 blocks
#define NROWS (NE * NL)                  // 50000 table rows (e,l)
#define NWBLK ((NROWS + TPB - 1) / TPB)  // 196 writer blocks
#define FLAGS_OFF (1u << 20)             // flags at d_ws + 1MB (T uses 800KB)
#define DONE_IDX 200

typedef unsigned u32x4 __attribute__((ext_vector_type(4)));

__device__ __forceinline__ unsigned magic_of(int i) {
    return 0xA5C37E19u ^ ((unsigned)i * 0x9E3779B1u);
}
#define DONE_MAGIC 0x5EC0FFEEu

// flag ops: RELAXED agent atomics -> plain sc1 dword load/store, NO buffer_wbl2
__device__ __forceinline__ void flag_store(unsigned* p, unsigned v) {
    __hip_atomic_store(p, v, __ATOMIC_RELAXED, __HIP_MEMORY_SCOPE_AGENT);
}
__device__ __forceinline__ unsigned flag_load(unsigned* p) {
    return __hip_atomic_load(p, __ATOMIC_RELAXED, __HIP_MEMORY_SCOPE_AGENT);
}

// Single plain dispatch.
//  Phase A: threads g<50000 build T[e][l][h] fp16; store WRITE-THROUGH to L3
//           (global_store_dwordx4 sc0 sc1) -- no dirty L2, no wbl2 on release.
//  Barrier: writers drain vmcnt then relaxed-store magic flag; block 0
//           aggregates 196 flags into one DONE flag; others poll DONE only.
//  Phase B: 5 x 16B T-gathers per pair via sc0 sc1 loads (bypass stale L2,
//           hit L3). 4x fewer 16B granules than the 17.1us baseline.
__global__ __launch_bounds__(256, 4) void edge_onepass(
    const float* __restrict__ F,    // [E, D]
    const float* __restrict__ Wg,   // [L+1, H*D]
    const int* __restrict__ sp,     // [NPAIR, L] int32
    float* __restrict__ out,        // [H, NPAIR]
    __half* __restrict__ T,         // [NROWS, NH] fp16 workspace
    unsigned* __restrict__ flags)   // [256] workspace
{
    __shared__ int spL[TPB * NL];   // 1280 ints
    const int tid = threadIdx.x;
    const int bid = blockIdx.x;
    const int g = bid * TPB + tid;

    // ---- issue sp staging first: latency hides under phase A + barrier ----
    const int4* __restrict__ spv = (const int4*)(sp + (size_t)bid * (TPB * NL));
    int4* spd = (int4*)spL;
#pragma unroll
    for (int i = 0; i < 2; ++i) {
        const int k = tid + i * TPB;
        if (k < (TPB * NL) / 4) spd[k] = spv[k];
    }

    // ---- Phase A: build fp16 table (blocks 0..195) ----
    if (g < NROWS) {
        const int e = g / NL;
        const int l = g - e * NL;
        const float4* __restrict__ fp = (const float4*)(F + (size_t)e * ND);
        const float4 f0 = fp[0], f1 = fp[1], f2 = fp[2], f3 = fp[3];
        const float* __restrict__ w0 = Wg + NH * ND + l * NH * ND;  // W row 1+l

        union { u32x4 u4; __half2 h2[4]; } s;
#pragma unroll
        for (int hh = 0; hh < 4; ++hh) {
            float r2[2];
#pragma unroll
            for (int k = 0; k < 2; ++k) {
                const int h = hh * 2 + k;
                const float4* __restrict__ wp = (const float4*)(w0 + h * ND);
                const float4 wa = wp[0], wb = wp[1], wc = wp[2], wd = wp[3];
                float a;
                a  = f0.x * wa.x + f0.y * wa.y + f0.z * wa.z + f0.w * wa.w;
                a += f1.x * wb.x + f1.y * wb.y + f1.z * wb.z + f1.w * wb.w;
                a += f2.x * wc.x + f2.y * wc.y + f2.z * wc.z + f2.w * wc.w;
                a += f3.x * wd.x + f3.y * wd.y + f3.z * wd.z + f3.w * wd.w;
                r2[k] = a;
            }
            s.h2[hh] = __floats2half2_rn(r2[0], r2[1]);
        }
        const unsigned long long ta =
            (unsigned long long)(uintptr_t)(T + (size_t)g * NH);
        // write-through to L3: visible device-wide once vmcnt retires
        asm volatile("global_store_dwordx4 %0, %1, off sc0 sc1"
                     :: "v"(ta), "v"(s.u4) : "memory");
    }

    // ---- writer signal ----
    if (bid < NWBLK) {
        asm volatile("s_waitcnt vmcnt(0)" ::: "memory");  // T acked at L3
        __syncthreads();
        if (tid == 0) flag_store(&flags[bid], magic_of(bid));
    }

    // ---- barrier: block 0 aggregates; everyone else polls DONE ----
    if (bid == 0) {
        if (tid < NWBLK) {
            const unsigned want = magic_of(tid);
            while (flag_load(&flags[tid]) != want)
                __builtin_amdgcn_s_sleep(1);
        }
        __syncthreads();
        if (tid == 0) flag_store(&flags[DONE_IDX], DONE_MAGIC);
    } else {
        if (tid == 0) {
            while (flag_load(&flags[DONE_IDX]) != DONE_MAGIC)
                __builtin_amdgcn_s_sleep(4);
        }
        __syncthreads();   // also orders spL staging before phase B reads
    }

    // ---- Phase B: gather + masked mean ----
    int e[NL];
#pragma unroll
    for (int l = 0; l < NL; ++l) e[l] = spL[tid * NL + l];  // stride-5, conflict-free

    // issue all 5 sc-bypass 16B loads, then one waitcnt tied via dataflow
    u32x4 t0, t1, t2, t3, t4;
    {
        unsigned long long a[NL];
#pragma unroll
        for (int l = 0; l < NL; ++l) {
            const int row = ((e[l] >= 0) ? e[l] : 0) * NL + l;
            a[l] = (unsigned long long)(uintptr_t)(T + (size_t)row * NH);
        }
        asm volatile("global_load_dwordx4 %0, %1, off sc0 sc1" : "=v"(t0) : "v"(a[0]));
        asm volatile("global_load_dwordx4 %0, %1, off sc0 sc1" : "=v"(t1) : "v"(a[1]));
        asm volatile("global_load_dwordx4 %0, %1, off sc0 sc1" : "=v"(t2) : "v"(a[2]));
        asm volatile("global_load_dwordx4 %0, %1, off sc0 sc1" : "=v"(t3) : "v"(a[3]));
        asm volatile("global_load_dwordx4 %0, %1, off sc0 sc1" : "=v"(t4) : "v"(a[4]));
        asm volatile("s_waitcnt vmcnt(0)"
                     : "+v"(t0), "+v"(t1), "+v"(t2), "+v"(t3), "+v"(t4));
        __builtin_amdgcn_sched_barrier(0);
    }

    float acc[NH];
#pragma unroll
    for (int h = 0; h < NH; ++h) acc[h] = 0.f;
    float cnt = 0.f;

    const u32x4 tv[NL] = {t0, t1, t2, t3, t4};
#pragma unroll
    for (int l = 0; l < NL; ++l) {
        const float m = (e[l] >= 0) ? 1.f : 0.f;
        cnt += m;
#pragma unroll
        for (int hh = 0; hh < 4; ++hh) {
            const unsigned u = tv[l][hh];
            __half2 p; __builtin_memcpy(&p, &u, 4);
            const float2 v = __half22float2(p);
            acc[hh * 2 + 0] += m * v.x;
            acc[hh * 2 + 1] += m * v.y;
        }
    }

    const float r = 1.0f / fmaxf(cnt, 1.f);
    const size_t p = (size_t)g;
#pragma unroll
    for (int h = 0; h < NH; ++h)
        __builtin_nontemporal_store(acc[h] * r, out + (size_t)h * NPAIR + p);
}

extern "C" void kernel_launch(void* const* d_in, const int* in_sizes, int n_in,
                              void* d_out, int out_size, void* d_ws, size_t ws_size,
                              hipStream_t stream) {
    (void)in_sizes; (void)n_in; (void)out_size; (void)ws_size;
    const float* F  = (const float*)d_in[0];   // edge_features_s [E, D]
    const float* Wg = (const float*)d_in[1];   // edge_weights [L+1, H*D]
    const int*   sp = (const int*)d_in[2];     // shortest_path_edges [N,N,L] int32
    float* out = (float*)d_out;                // [H, N, N]
    __half* T = (__half*)d_ws;                 // 800 KB table
    unsigned* flags = (unsigned*)((char*)d_ws + FLAGS_OFF);

    edge_onepass<<<GRID, TPB, 0, stream>>>(F, Wg, sp, out, T, flags);
}